// Round 6
// baseline (316.410 us; speedup 1.0000x reference)
//
#include <hip/hip_runtime.h>
#include <stdint.h>

#define B_   4
#define T_   32
#define N_   4096
#define F_   16
#define G_   64      // B*F
#define M_   128
#define K_   32
#define C0_  64
#define C1_  128

typedef short  short8 __attribute__((ext_vector_type(8)));
typedef float  f32x4  __attribute__((ext_vector_type(4)));

static __device__ __forceinline__ short f2bf(float x) {
    union { float f; unsigned u; } v; v.f = x;
    unsigned r = (v.u + 0x7FFFu + ((v.u >> 16) & 1u)) >> 16;
    return (short)r;
}
static __device__ __forceinline__ float bf2f(short h) {
    union { float f; unsigned u; } v; v.u = ((unsigned)(unsigned short)h) << 16;
    return v.f;
}

// u64 combine via DPP (both 32b halves). All ctrls used have valid sources
// for every lane (quad_perm / row_ror), so old=0 is never observed.
template<int CTRL>
static __device__ __forceinline__ unsigned long long dpp_u64(unsigned long long v) {
    int lo = __builtin_amdgcn_update_dpp(0, (int)(unsigned)v,         CTRL, 0xF, 0xF, false);
    int hi = __builtin_amdgcn_update_dpp(0, (int)(unsigned)(v >> 32), CTRL, 0xF, 0xF, false);
    return ((unsigned long long)(unsigned)hi << 32) | (unsigned)lo;
}

// ---------------------------------------------------------------------------
// Kernel 1: FPS (blocks 0..63) + Wm hi/lo split (blocks 64..67).
// FPS: 256 thr, 16 pts/thread. Per iter: dist update + packed u64 key argmax;
// all-lanes wave reduce (quad_perm xor1,xor2 + row_ror 4,8 + shfl_xor 16,32);
// the winner LANE writes key + its coords (float4) to LDS; one barrier;
// 4-entry combine carries coords alongside the key (no coord cache, no
// dependent coord fetch). Bit-exact fp32 (contract off, reference eval
// order); key is (bits(d)<<32)|(4095-i): strict max == first-occurrence
// argmax (reference semantics).
// ---------------------------------------------------------------------------
__global__ __launch_bounds__(256) void fps_kernel(const float* __restrict__ xyzs,
                                                  float* __restrict__ anchors,
                                                  float* __restrict__ out_xyz,
                                                  const float* __restrict__ Wm,
                                                  short* __restrict__ Bhi_g,
                                                  short* __restrict__ Blo_g)
{
#pragma clang fp contract(off)
    if (blockIdx.x >= G_) {
        // ---- Wm split role: 4 blocks x 256 threads = 1024 tasks ----
        int id = (blockIdx.x - G_) * 256 + threadIdx.x;
        int o = id >> 3, c = id & 7;
        const float* wp = Wm + o * C0_ + c * 8;
        short8 hv, lv;
#pragma unroll
        for (int e = 0; e < 8; ++e) {
            float v = wp[e];
            short h = f2bf(v);
            short l = f2bf(v - bf2f(h));
            hv[e] = h; lv[e] = l;
        }
        int dst = o * C0_ + c * 8;
        *reinterpret_cast<short8*>(&Bhi_g[dst]) = hv;
        *reinterpret_cast<short8*>(&Blo_g[dst]) = lv;
        return;
    }

    const int g = blockIdx.x;
    const int b = g >> 4, f = g & 15;
    const float* base = xyzs + ((size_t)(b * T_ + 2 * f) * N_) * 3;
    const int t = threadIdx.x;       // 0..255
    const int wid = t >> 6;          // 0..3

    __shared__ unsigned long long skey[2][4];
    __shared__ float4 scrd[2][4];

    float x[16], y[16], z[16], dist[16];
#pragma unroll
    for (int j = 0; j < 16; ++j) {
        int p = j * 256 + t;
        x[j] = base[p * 3 + 0];
        y[j] = base[p * 3 + 1];
        z[j] = base[p * 3 + 2];
        dist[j] = 1e10f;
    }

    float px = base[0], py = base[1], pz = base[2];   // anchor 0 = point 0
    float rx = 0.f, ry = 0.f, rz = 0.f;               // my buffered anchor
    if (t == 0) { rx = px; ry = py; rz = pz; }

    for (int it = 1; it < M_; ++it) {
        float bd = -1.0f; int bi = 0;
#pragma unroll
        for (int j = 0; j < 16; ++j) {
            float dx = x[j] - px;
            float dy = y[j] - py;
            float dz = z[j] - pz;
            float d = dx * dx + dy * dy;    // contract off: plain mul/add
            d = d + dz * dz;
            float nd = fminf(dist[j], d);
            dist[j] = nd;
            if (nd > bd) { bd = nd; bi = j * 256 + t; }  // ascending p: first max kept
        }
        unsigned long long mykey =
            ((unsigned long long)__float_as_uint(bd) << 32) | (unsigned)(N_ - 1 - bi);
        unsigned long long key = mykey, k2;
        k2 = dpp_u64<0xB1>(key);  key = (k2 > key) ? k2 : key;   // quad_perm xor1
        k2 = dpp_u64<0x4E>(key);  key = (k2 > key) ? k2 : key;   // quad_perm xor2
        k2 = dpp_u64<0x124>(key); key = (k2 > key) ? k2 : key;   // row_ror:4
        k2 = dpp_u64<0x128>(key); key = (k2 > key) ? k2 : key;   // row_ror:8 -> row max, all 16 lanes
        k2 = __shfl_xor(key, 16); key = (k2 > key) ? k2 : key;
        k2 = __shfl_xor(key, 32); key = (k2 > key) ? k2 : key;   // wave max, ALL lanes
        const int par = it & 1;
        if (mykey == key) {
            // exactly one lane per wave: extract my winning candidate's coords
            float wx = x[0], wy = y[0], wz = z[0];
#pragma unroll
            for (int j = 1; j < 16; ++j) {
                if (bi == j * 256 + t) { wx = x[j]; wy = y[j]; wz = z[j]; }
            }
            skey[par][wid] = key;
            scrd[par][wid] = make_float4(wx, wy, wz, 0.f);
        }
        __syncthreads();
        unsigned long long ck = skey[par][0];
        float4 cc = scrd[par][0];
#pragma unroll
        for (int w = 1; w < 4; ++w) {
            unsigned long long ok = skey[par][w];
            float4 oc = scrd[par][w];
            if (ok > ck) { ck = ok; cc = oc; }
        }
        px = cc.x; py = cc.y; pz = cc.z;
        if (t == it) { rx = px; ry = py; rz = pz; }
    }

    if (t < M_) {
        size_t ao = ((size_t)g * M_ + t) * 3;
        anchors[ao + 0] = rx; anchors[ao + 1] = ry; anchors[ao + 2] = rz;
        out_xyz[ao + 0] = rx; out_xyz[ao + 1] = ry; out_xyz[ao + 2] = rz;
    }
}

// ---------------------------------------------------------------------------
// Kernel 2: Ball query, chunked. One wave per (g, dt, m). 8 iterations' loads
// + ballots issued together (pipelined), then VALU-only prefix-pack; exit
// check per chunk. Semantics identical to first-K-in-radius + fill.
// ---------------------------------------------------------------------------
__global__ __launch_bounds__(256) void ballq_kernel(const float* __restrict__ xyzs,
                                                    const float* __restrict__ anchors,
                                                    int* __restrict__ widx)
{
#pragma clang fp contract(off)
    const float R2 = 0.0225f;
    const int wave = (blockIdx.x << 2) + (threadIdx.x >> 6);
    const int lane = threadIdx.x & 63;
    const int m   = wave % M_;
    const int gd  = wave / M_;      // g*3 + dti
    const int dti = gd % 3;
    const int g   = gd / 3;
    const int b = g >> 4, f = g & 15;
    int tn = 2 * f + dti - 1;
    if (tn < 0) tn = 0;
    const float* nb = xyzs + ((size_t)(b * T_ + tn) * N_) * 3;
    const float* aw = anchors + ((size_t)g * M_ + m) * 3;
    const float ax = aw[0], ay = aw[1], az = aw[2];

    __shared__ int sbuf[4][K_];
    int* buf = sbuf[threadIdx.x >> 6];
    const unsigned long long lanebit = 1ULL << lane;

    int filled = 0;
    for (int cb = 0; cb < 8 && filled < K_; ++cb) {
        unsigned long long mk[8];
#pragma unroll
        for (int u = 0; u < 8; ++u) {
            int p = cb * 512 + u * 64 + lane;
            float dx = nb[p * 3 + 0] - ax;
            float dy = nb[p * 3 + 1] - ay;
            float dz = nb[p * 3 + 2] - az;
            float d2 = dx * dx + dy * dy;
            d2 = d2 + dz * dz;
            mk[u] = __ballot(d2 < R2);
        }
#pragma unroll
        for (int u = 0; u < 8; ++u) {
            if (mk[u] & lanebit) {
                int slot = filled + __popcll(mk[u] & (lanebit - 1ULL));
                if (slot < K_) buf[slot] = cb * 512 + u * 64 + lane;
            }
            filled += __popcll(mk[u]);
        }
    }
    __syncthreads();
    if (lane < K_) {
        int first = (filled > 0) ? buf[0] : 0;
        int v = (lane < filled) ? buf[lane] : first;
        widx[(size_t)wave * K_ + lane] = v;
    }
}

// ---------------------------------------------------------------------------
// Kernel 3: MLP via MFMA, B-in-registers. One block per (g, m-pair): 4096
// blocks, 256 thr (4 waves). Wave = (m_local, N-half): 6 M-tiles x 4 N-tiles,
// 96 MFMA. B-frags (Wm hi/lo, plain layout) loaded global->reg at entry; only
// A (h1, 24 KB) staged in LDS (XOR-swizzled). Outputs packed via 1 KB LDS ->
// coalesced float2 stores.
// ---------------------------------------------------------------------------
__global__ __launch_bounds__(256, 2) void mlp_kernel(const float* __restrict__ xyzs,
                                                     const float* __restrict__ Wd,
                                                     const short* __restrict__ Bhi_g,
                                                     const short* __restrict__ Blo_g,
                                                     const float* __restrict__ anchors,
                                                     const int* __restrict__ widx,
                                                     float* __restrict__ out_feat)
{
    const int t   = threadIdx.x;
    const int blk = blockIdx.x;          // G * 64
    const int g   = blk >> 6;
    const int m0  = (blk & 63) * 2;
    const int b = g >> 4, f = g & 15;

    const int lane = t & 63;
    const int w    = t >> 6;             // 0..3
    const int wml  = w & 1;              // m_local
    const int wn   = w >> 1;             // N-half (64 cols)
    const int row0 = lane & 15;
    const int kg   = lane >> 4;

    __shared__ __align__(16) short Ahi[192 * C0_];   // 24 KB
    __shared__ float wd_s[C0_ * 4];                  // 1 KB
    __shared__ float pmf[2][C1_];                    // 1 KB

    // --- B fragments from global (plain layout), issued immediately.
    short8 bh[4][2], bl[4][2];   // [nt][ks]
#pragma unroll
    for (int nt = 0; nt < 4; ++nt) {
        int o = wn * 64 + nt * 16 + row0;
#pragma unroll
        for (int ks = 0; ks < 2; ++ks) {
            int off = o * C0_ + (ks * 4 + kg) * 8;
            bh[nt][ks] = *reinterpret_cast<const short8*>(&Bhi_g[off]);
            bl[nt][ks] = *reinterpret_cast<const short8*>(&Blo_g[off]);
        }
    }

    wd_s[t] = Wd[t];

    // --- gather: thread t < 192 owns row t = ml*96 + dti*32 + k.
    float dx = 0.f, dy = 0.f, dz = 0.f, dt4 = 0.f;
    if (t < 192) {
        int ml  = (t >= 96) ? 1 : 0;
        int rr  = t - ml * 96;
        int dti = rr >> 5, k = rr & 31;
        int m   = m0 + ml;
        int tn  = 2 * f + dti - 1;
        if (tn < 0) tn = 0;
        const float* nb = xyzs + ((size_t)(b * T_ + tn) * N_) * 3;
        int idx = widx[((size_t)(g * 3 + dti) * M_ + m) * K_ + k];
        const float* aw = anchors + ((size_t)g * M_ + m) * 3;
        dx = nb[idx * 3 + 0] - aw[0];
        dy = nb[idx * 3 + 1] - aw[1];
        dz = nb[idx * 3 + 2] - aw[2];
        dt4 = (float)(dti - 1);
    }
    __syncthreads();   // wd_s ready

    // --- h1 = relu(Wd . d4) -> bf16, XOR-swizzled LDS rows.
    if (t < 192) {
#pragma unroll
        for (int u = 0; u < 8; ++u) {
            short8 hv;
#pragma unroll
            for (int e = 0; e < 8; ++e) {
                float4 wv = *reinterpret_cast<const float4*>(&wd_s[(u * 8 + e) * 4]);
                float s = dx * wv.x + dy * wv.y + dz * wv.z + dt4 * wv.w;
                hv[e] = f2bf(fmaxf(s, 0.0f));
            }
            *reinterpret_cast<short8*>(&Ahi[t * C0_ + ((u ^ (t & 7)) << 3)]) = hv;
        }
    }
    __syncthreads();

    // --- MFMA: D[rows 96 of wml][cols 64 of wn].
    f32x4 acc[6][4];
#pragma unroll
    for (int mt = 0; mt < 6; ++mt)
#pragma unroll
        for (int nt = 0; nt < 4; ++nt) {
            acc[mt][nt][0] = 0.f; acc[mt][nt][1] = 0.f;
            acc[mt][nt][2] = 0.f; acc[mt][nt][3] = 0.f;
        }

#pragma unroll
    for (int ks = 0; ks < 2; ++ks) {
        int chunk = ks * 4 + kg;
        short8 ah[6];
#pragma unroll
        for (int mt = 0; mt < 6; ++mt) {
            int r = wml * 96 + mt * 16 + row0;
            ah[mt] = *reinterpret_cast<const short8*>(&Ahi[r * C0_ + ((chunk ^ (r & 7)) << 3)]);
        }
#pragma unroll
        for (int mt = 0; mt < 6; ++mt)
#pragma unroll
            for (int nt = 0; nt < 4; ++nt) {
                acc[mt][nt] = __builtin_amdgcn_mfma_f32_16x16x32_bf16(ah[mt], bh[nt][ks], acc[mt][nt], 0, 0, 0);
                acc[mt][nt] = __builtin_amdgcn_mfma_f32_16x16x32_bf16(ah[mt], bl[nt][ks], acc[mt][nt], 0, 0, 0);
            }
    }

    // --- epilogue: per (dti, col) max over 32 k-rows (2 tiles x 4 regs x
    //     4 lane-groups), relu, sum dts; pack both m's -> float2 stores.
#pragma unroll
    for (int nt = 0; nt < 4; ++nt) {
        float fs = 0.f;
#pragma unroll
        for (int dti = 0; dti < 3; ++dti) {
            f32x4 a0 = acc[dti * 2 + 0][nt];
            f32x4 a1 = acc[dti * 2 + 1][nt];
            float mv = fmaxf(fmaxf(fmaxf(a0[0], a0[1]), fmaxf(a0[2], a0[3])),
                             fmaxf(fmaxf(a1[0], a1[1]), fmaxf(a1[2], a1[3])));
            mv = fmaxf(mv, 0.0f);
            mv = fmaxf(mv, __shfl_xor(mv, 16));
            mv = fmaxf(mv, __shfl_xor(mv, 32));
            fs += mv;   // dt order -1,0,+1 = reference accumulation order
        }
        if (lane < 16) pmf[wml][wn * 64 + nt * 16 + lane] = fs;
    }
    __syncthreads();

    if (t < C1_) {
        float2 v = make_float2(pmf[0][t], pmf[1][t]);
        *reinterpret_cast<float2*>(&out_feat[((size_t)g * C1_ + t) * M_ + m0]) = v;
    }
}

// ---------------------------------------------------------------------------
extern "C" void kernel_launch(void* const* d_in, const int* in_sizes, int n_in,
                              void* d_out, int out_size, void* d_ws, size_t ws_size,
                              hipStream_t stream)
{
    (void)in_sizes; (void)n_in; (void)out_size; (void)ws_size;
    const float* xyzs = (const float*)d_in[0];
    const float* Wd   = (const float*)d_in[1];
    const float* Wm   = (const float*)d_in[2];
    float* out = (float*)d_out;

    char* ws = (char*)d_ws;
    short* Bhi_g   = (short*)ws;                              // 16 KB
    short* Blo_g   = (short*)(ws + 16384);                    // 16 KB
    float* anchors = (float*)(ws + 32768);                    // G*M*3 floats
    int*   widx    = (int*)(ws + 32768 + (size_t)G_ * M_ * 3 * 4);

    float* out_xyz  = out;                 // (B,F,M,3) = (G,M,3)
    float* out_feat = out + G_ * M_ * 3;   // (B,F,C1,M) = (G,C1,M)

    hipLaunchKernelGGL(fps_kernel,    dim3(G_ + 4),           dim3(256), 0, stream,
                       xyzs, anchors, out_xyz, Wm, Bhi_g, Blo_g);
    hipLaunchKernelGGL(ballq_kernel,  dim3(G_ * 3 * M_ / 4),  dim3(256), 0, stream, xyzs, anchors, widx);
    hipLaunchKernelGGL(mlp_kernel,    dim3(G_ * 64),          dim3(256), 0, stream,
                       xyzs, Wd, Bhi_g, Blo_g, anchors, widx, out_feat);
}